// Round 3
// baseline (3374.944 us; speedup 1.0000x reference)
//
#include <hip/hip_runtime.h>
#include <cstdint>
#include <cstddef>
#include <cmath>

#define NLAYER 6
#define NH 12
#define DMODEL 384
#define DHEAD 32
#define DFFN 1536
#define BATCH 64
#define SEQ 512
#define NROWS (BATCH*SEQ)   // 32768
#define DQKV 1152           // fused q|k|v row length
#define FFN_CHUNK 16384     // 2 chunks; h buffer reused (sequential chunks)

typedef unsigned short ushort;
typedef __attribute__((ext_vector_type(8))) short bf16x8;   // 8 bf16 = 4 VGPRs
typedef __attribute__((ext_vector_type(4))) float f32x4;

// ---------------------------------------------------------------- utilities

__device__ inline float bf2f(ushort u) {
    union { unsigned int i; float f; } c; c.i = ((unsigned int)u) << 16; return c.f;
}
__device__ inline ushort f2bf(float f) {
    union { float f; unsigned int i; } c; c.f = f;
    unsigned int i = c.i;
    unsigned int lsb = (i >> 16) & 1u;
    i += 0x7fffu + lsb;          // round-to-nearest-even
    return (ushort)(i >> 16);
}

__device__ inline float wave_reduce_sum(float v) {
    #pragma unroll
    for (int m = 32; m >= 1; m >>= 1) v += __shfl_xor(v, m, 64);
    return v;
}

__device__ inline float sigmoidf(float x) { return 1.0f / (1.0f + expf(-x)); }

__device__ inline float gelu_tanh(float x) {
    const float c = 0.7978845608028654f; // sqrt(2/pi)
    float t = tanhf(c * (x + 0.044715f * x * x * x));
    return 0.5f * x * (1.0f + t);
}

// async global->LDS, 16 bytes per lane; lds base must be wave-uniform
__device__ inline void async16(const ushort* g, ushort* l) {
    __builtin_amdgcn_global_load_lds(
        (const __attribute__((address_space(1))) unsigned int*)g,
        (__attribute__((address_space(3))) unsigned int*)l,
        16, 0, 0);
}

// ---------------------------------------------------------------- weight convert+transpose
// W fp32 [L][K][N] -> WT bf16 rows of K elements; layer stride lStride,
// dest row offset nOff (fused QKV packing).
__global__ __launch_bounds__(256)
void convT_kernel(const float* __restrict__ W, ushort* __restrict__ WT, int K, int N,
                  size_t lStride, int nOff)
{
    __shared__ float t[32][33];
    int k0 = blockIdx.x * 32, n0 = blockIdx.y * 32, L = blockIdx.z;
    const float* Wl = W + (size_t)L * K * N;
    ushort* WTl = WT + (size_t)L * lStride;
    int tx = threadIdx.x & 31, ty = threadIdx.x >> 5;   // 32 x 8
    #pragma unroll
    for (int i = 0; i < 4; ++i)
        t[ty + 8 * i][tx] = Wl[(size_t)(k0 + ty + 8 * i) * N + n0 + tx];
    __syncthreads();
    #pragma unroll
    for (int i = 0; i < 4; ++i)
        WTl[(size_t)(nOff + n0 + ty + 8 * i) * K + k0 + tx] = f2bf(t[tx][ty + 8 * i]);
}

// ---------------------------------------------------------------- fused qkv bias concat: [L][1152]
__global__ __launch_bounds__(384)
void biascat_kernel(const float* __restrict__ bq, const float* __restrict__ bk,
                    const float* __restrict__ bv, float* __restrict__ dst)
{
    int L = blockIdx.x, d = threadIdx.x;
    dst[(size_t)L * DQKV + d]             = bq[(size_t)L * DMODEL + d];
    dst[(size_t)L * DQKV + DMODEL + d]    = bk[(size_t)L * DMODEL + d];
    dst[(size_t)L * DQKV + 2*DMODEL + d]  = bv[(size_t)L * DMODEL + d];
}

// ---------------------------------------------------------------- embedding + LN (writes fp32 x and bf16 xb)
__global__ __launch_bounds__(256)
void embed_ln_kernel(const int* __restrict__ ids, const float* __restrict__ we,
                     const float* __restrict__ pe, const float* __restrict__ te,
                     const float* __restrict__ g, const float* __restrict__ bb,
                     float* __restrict__ x, ushort* __restrict__ xb)
{
    int row = blockIdx.x * 4 + (threadIdx.x >> 6);
    int lane = threadIdx.x & 63;
    int l = row & (SEQ - 1);
    int id = ids[row];
    float vals[6];
    float s = 0.f;
    #pragma unroll
    for (int t = 0; t < 6; ++t) {
        int d = lane + 64 * t;
        float v = we[(size_t)id * DMODEL + d] + pe[(size_t)l * DMODEL + d] + te[d];
        vals[t] = v; s += v;
    }
    s = wave_reduce_sum(s);
    float m = s * (1.0f / DMODEL);
    float s2 = 0.f;
    #pragma unroll
    for (int t = 0; t < 6; ++t) { float dd = vals[t] - m; s2 += dd * dd; }
    s2 = wave_reduce_sum(s2);
    float rs = rsqrtf(s2 * (1.0f / DMODEL) + 1e-12f);
    #pragma unroll
    for (int t = 0; t < 6; ++t) {
        int d = lane + 64 * t;
        float val = (vals[t] - m) * rs * g[d] + bb[d];
        x[(size_t)row * DMODEL + d] = val;
        xb[(size_t)row * DMODEL + d] = f2bf(val);
    }
}

// ---------------------------------------------------------------- residual add + LN (fp32 x in-place; bf16 branch; writes xb)
__global__ __launch_bounds__(256)
void add_ln_kernel(float* x, ushort* __restrict__ xb, const ushort* __restrict__ r,
                   const float* __restrict__ g, const float* __restrict__ bb)
{
    int row = blockIdx.x * 4 + (threadIdx.x >> 6);
    int lane = threadIdx.x & 63;
    float vals[6];
    float s = 0.f;
    #pragma unroll
    for (int t = 0; t < 6; ++t) {
        int d = lane + 64 * t;
        size_t idx = (size_t)row * DMODEL + d;
        float v = x[idx] + bf2f(r[idx]);
        vals[t] = v; s += v;
    }
    s = wave_reduce_sum(s);
    float m = s * (1.0f / DMODEL);
    float s2 = 0.f;
    #pragma unroll
    for (int t = 0; t < 6; ++t) { float dd = vals[t] - m; s2 += dd * dd; }
    s2 = wave_reduce_sum(s2);
    float rs = rsqrtf(s2 * (1.0f / DMODEL) + 1e-12f);
    #pragma unroll
    for (int t = 0; t < 6; ++t) {
        int d = lane + 64 * t;
        size_t idx = (size_t)row * DMODEL + d;
        float val = (vals[t] - m) * rs * g[d] + bb[d];
        x[idx] = val;
        xb[idx] = f2bf(val);
    }
}

// ---------------------------------------------------------------- bf16 MFMA GEMM, async-staged  [verified R7]
// A row stride Astride (elements) may differ from K (strided o-section reads).
template<typename TC>
__global__ __launch_bounds__(256)
void gemm_mfma(const ushort* __restrict__ A, const ushort* __restrict__ WT,
               const float* __restrict__ bias, TC* __restrict__ C,
               int M, int N, int K, int Astride, int act)
{
    __shared__ __align__(16) ushort As[128 * 64];   // 16 KB
    __shared__ __align__(16) ushort Bs[128 * 64];   // 16 KB
    int tid = threadIdx.x;
    int lane = tid & 63, wv = tid >> 6;
    int waveM = wv >> 1, waveN = wv & 1;
    int lm = lane & 15, quad = lane >> 4;
    int row0 = blockIdx.x * 128, col0 = blockIdx.y * 128;
    int srow = lane >> 3, sseg = lane & 7;          // staging: 8 rows x 8 segs

    f32x4 acc[4][4] = {};

    for (int k0 = 0; k0 < K; k0 += 64) {
        __syncthreads();
        #pragma unroll
        for (int i = 0; i < 4; ++i) {
            int r = wv * 32 + i * 8 + srow;
            int sg = sseg ^ (r & 7);
            async16(A  + (size_t)(row0 + r) * Astride + k0 + sg * 8, &As[(wv * 32 + i * 8) * 64]);
            async16(WT + (size_t)(col0 + r) * K + k0 + sg * 8, &Bs[(wv * 32 + i * 8) * 64]);
        }
        __syncthreads();

        #pragma unroll
        for (int ks = 0; ks < 2; ++ks) {
            int physA = ((ks * 4 + quad) ^ (lm & 7)) * 8;
            bf16x8 af[4], bf[4];
            #pragma unroll
            for (int mt = 0; mt < 4; ++mt)
                af[mt] = *(const bf16x8*)&As[(waveM * 64 + mt * 16 + lm) * 64 + physA];
            #pragma unroll
            for (int nt = 0; nt < 4; ++nt)
                bf[nt] = *(const bf16x8*)&Bs[(waveN * 64 + nt * 16 + lm) * 64 + physA];
            #pragma unroll
            for (int mt = 0; mt < 4; ++mt)
                #pragma unroll
                for (int nt = 0; nt < 4; ++nt)
                    acc[mt][nt] = __builtin_amdgcn_mfma_f32_16x16x32_bf16(af[mt], bf[nt], acc[mt][nt], 0, 0, 0);
        }
    }

    #pragma unroll
    for (int mt = 0; mt < 4; ++mt) {
        #pragma unroll
        for (int nt = 0; nt < 4; ++nt) {
            int col = col0 + waveN * 64 + nt * 16 + lm;
            float bv = bias[col];
            #pragma unroll
            for (int r = 0; r < 4; ++r) {
                int row = row0 + waveM * 64 + mt * 16 + quad * 4 + r;
                float val = acc[mt][nt][r] + bv;
                if (act == 1) val = gelu_tanh(gelu_tanh(val));
                if constexpr (sizeof(TC) == 2)
                    C[(size_t)row * N + col] = f2bf(val);
                else
                    C[(size_t)row * N + col] = val;
            }
        }
    }
}

// ---------------------------------------------------------------- beta: wave per row, coalesced bf16 x  [verified R7]
__global__ __launch_bounds__(256)
void beta_kernel(const ushort* __restrict__ xb, const float* __restrict__ Wb,
                 const float* __restrict__ mask, float* __restrict__ beta)
{
    int row = blockIdx.x * 4 + (threadIdx.x >> 6);
    int lane = threadIdx.x & 63;
    float xr[6];
    #pragma unroll
    for (int t = 0; t < 6; ++t) xr[t] = bf2f(xb[(size_t)row * DMODEL + lane + 64 * t]);
    float mine = 0.f;
    #pragma unroll
    for (int h = 0; h < NH; ++h) {
        float p = 0.f;
        #pragma unroll
        for (int t = 0; t < 6; ++t) p += xr[t] * Wb[(size_t)(lane + 64 * t) * NH + h];
        p = wave_reduce_sum(p);
        if (lane == h) mine = p;
    }
    if (lane < NH) beta[(size_t)row * NH + lane] = sigmoidf(mine) * mask[row];
}

// ---------------------------------------------------------------- delta-rule scan v6: one wave per (b,h)
// lane = (kh, n): kh = k-half (16-deep k slice), n = state column. Lane owns
// Sf/Ss[k in kh*16..+16][n] as 8 float2 (k-pairs, v_pk_fma). Per-step k/q
// LDS reads are half-row broadcasts (conflict-free); pf/ps/o need one
// shfl_xor(.,32) cross-half reduce. q/k l2norm + k*mask fused into staging
// (norm_qk kernel eliminated). Next tile software-prefetched into registers
// so the global-load latency hides under the 32-step compute.
// o writes into the q-section of qkv (q rows staged before overwrite; safe:
// o-writes touch rows < t0+32, prefetch reads rows >= t0+32).
#define SCAN_T 32
#define SPAD 36
__global__ __launch_bounds__(64)
void scan_kernel(const ushort* __restrict__ qkv, const float* __restrict__ beta,
                 const float* __restrict__ mask,
                 const float* __restrict__ dfast, const float* __restrict__ dslow,
                 ushort* __restrict__ o)
{
    __shared__ __align__(16) float qs[SCAN_T][SPAD];
    __shared__ __align__(16) float ks[SCAN_T][SPAD];
    __shared__ __align__(16) float vs[SCAN_T][SPAD];
    __shared__ float bs[SCAN_T];

    int bh = blockIdx.x;
    int b = bh / NH, h = bh % NH;
    int lane = threadIdx.x;
    int kh = lane >> 5, n = lane & 31;
    int kh16 = kh << 4;

    float gf = sigmoidf(dfast[h]);
    float gsl = sigmoidf(dslow[h]);
    float2 gf2 = make_float2(gf, gf), gs2 = make_float2(gsl, gsl);
    float2 Sf[8], Ss[8];
    #pragma unroll
    for (int j = 0; j < 8; ++j) { Sf[j] = make_float2(0.f, 0.f); Ss[j] = make_float2(0.f, 0.f); }

    // prefetch registers (tile t0: lane stages half of row t0+n)
    uint4 pq0, pq1, pk0, pk1, pv0, pv1;
    float pb, pmk;
    {
        size_t ra = (size_t)(b * SEQ + n) * DQKV + h * DHEAD + kh16;
        pq0 = *(const uint4*)(qkv + ra);
        pq1 = *(const uint4*)(qkv + ra + 8);
        pk0 = *(const uint4*)(qkv + ra + DMODEL);
        pk1 = *(const uint4*)(qkv + ra + DMODEL + 8);
        pv0 = *(const uint4*)(qkv + ra + 2 * DMODEL);
        pv1 = *(const uint4*)(qkv + ra + 2 * DMODEL + 8);
        pb  = beta[(size_t)(b * SEQ + n) * NH + h];
        pmk = mask[b * SEQ + n];
    }

    for (int t0 = 0; t0 < SEQ; t0 += SCAN_T) {
        __syncthreads();
        // ---- stage prefetched tile into LDS, fusing q/k l2norm and k*mask
        {
            ushort tq[16], tk[16], tv[16];
            *(uint4*)tq = pq0; *(uint4*)(tq + 8) = pq1;
            *(uint4*)tk = pk0; *(uint4*)(tk + 8) = pk1;
            *(uint4*)tv = pv0; *(uint4*)(tv + 8) = pv1;
            float qv[16], kv[16];
            float sq = 0.f, sk = 0.f;
            #pragma unroll
            for (int j = 0; j < 16; ++j) {
                qv[j] = bf2f(tq[j]); sq += qv[j] * qv[j];
                kv[j] = bf2f(tk[j]); sk += kv[j] * kv[j];
            }
            sq += __shfl_xor(sq, 32, 64);   // partner lane holds other k-half of same row
            sk += __shfl_xor(sk, 32, 64);
            float rq = 1.0f / (sqrtf(sq) + 1e-6f);
            float rk = pmk / (sqrtf(sk) + 1e-6f);
            #pragma unroll
            for (int s2 = 0; s2 < 4; ++s2) {
                float4 fq, fk, fv;
                fq.x = qv[s2*4+0]*rq; fq.y = qv[s2*4+1]*rq; fq.z = qv[s2*4+2]*rq; fq.w = qv[s2*4+3]*rq;
                fk.x = kv[s2*4+0]*rk; fk.y = kv[s2*4+1]*rk; fk.z = kv[s2*4+2]*rk; fk.w = kv[s2*4+3]*rk;
                fv.x = bf2f(tv[s2*4+0]); fv.y = bf2f(tv[s2*4+1]); fv.z = bf2f(tv[s2*4+2]); fv.w = bf2f(tv[s2*4+3]);
                *(float4*)&qs[n][kh16 + s2*4] = fq;
                *(float4*)&ks[n][kh16 + s2*4] = fk;
                *(float4*)&vs[n][kh16 + s2*4] = fv;
            }
            if (kh == 0) bs[n] = pb;
        }
        __syncthreads();

        // ---- prefetch next tile (consumed next iteration; hides HBM latency)
        if (t0 + SCAN_T < SEQ) {
            size_t ra = (size_t)(b * SEQ + t0 + SCAN_T + n) * DQKV + h * DHEAD + kh16;
            pq0 = *(const uint4*)(qkv + ra);
            pq1 = *(const uint4*)(qkv + ra + 8);
            pk0 = *(const uint4*)(qkv + ra + DMODEL);
            pk1 = *(const uint4*)(qkv + ra + DMODEL + 8);
            pv0 = *(const uint4*)(qkv + ra + 2 * DMODEL);
            pv1 = *(const uint4*)(qkv + ra + 2 * DMODEL + 8);
            pb  = beta[(size_t)(b * SEQ + t0 + SCAN_T + n) * NH + h];
            pmk = mask[b * SEQ + t0 + SCAN_T + n];
        }

        #pragma unroll 4
        for (int t = 0; t < SCAN_T; ++t) {
            float2 kt[8], qt[8];
            #pragma unroll
            for (int s2 = 0; s2 < 4; ++s2) {
                *(float4*)&kt[s2*2] = *(const float4*)&ks[t][kh16 + s2*4];
                *(float4*)&qt[s2*2] = *(const float4*)&qs[t][kh16 + s2*4];
            }
            float vt = vs[t][n], bt = bs[t];

            float2 pf0 = kt[0]*Sf[0], pf1 = kt[1]*Sf[1], pf2 = kt[2]*Sf[2], pf3 = kt[3]*Sf[3];
            float2 ps0 = kt[0]*Ss[0], ps1 = kt[1]*Ss[1], ps2 = kt[2]*Ss[2], ps3 = kt[3]*Ss[3];
            pf0 += kt[4]*Sf[4]; pf1 += kt[5]*Sf[5]; pf2 += kt[6]*Sf[6]; pf3 += kt[7]*Sf[7];
            ps0 += kt[4]*Ss[4]; ps1 += kt[5]*Ss[5]; ps2 += kt[6]*Ss[6]; ps3 += kt[7]*Ss[7];
            float2 pfv = (pf0 + pf1) + (pf2 + pf3);
            float2 psv = (ps0 + ps1) + (ps2 + ps3);
            float pft = pfv.x + pfv.y, pst = psv.x + psv.y;
            pft += __shfl_xor(pft, 32, 64);      // combine the two k-halves
            pst += __shfl_xor(pst, 32, 64);

            float cf = bt * (vt - pft), cs = bt * (vt - pst);
            float2 cf2 = make_float2(cf, cf), cs2 = make_float2(cs, cs);

            float2 o0 = make_float2(0.f, 0.f), o1 = o0, o2 = o0, o3 = o0;
            #pragma unroll
            for (int j = 0; j < 8; j += 4) {
                Sf[j]   = gf2*Sf[j]   + kt[j]*cf2;   Ss[j]   = gs2*Ss[j]   + kt[j]*cs2;
                Sf[j+1] = gf2*Sf[j+1] + kt[j+1]*cf2; Ss[j+1] = gs2*Ss[j+1] + kt[j+1]*cs2;
                Sf[j+2] = gf2*Sf[j+2] + kt[j+2]*cf2; Ss[j+2] = gs2*Ss[j+2] + kt[j+2]*cs2;
                Sf[j+3] = gf2*Sf[j+3] + kt[j+3]*cf2; Ss[j+3] = gs2*Ss[j+3] + kt[j+3]*cs2;
                o0 += qt[j]   * (Sf[j]   + Ss[j]);
                o1 += qt[j+1] * (Sf[j+1] + Ss[j+1]);
                o2 += qt[j+2] * (Sf[j+2] + Ss[j+2]);
                o3 += qt[j+3] * (Sf[j+3] + Ss[j+3]);
            }
            float2 ov = (o0 + o1) + (o2 + o3);
            float ott = ov.x + ov.y;
            ott += __shfl_xor(ott, 32, 64);      // combine the two k-halves
            if (lane < 32)
                o[(size_t)(b * SEQ + t0 + t) * DQKV + h * DHEAD + n] = f2bf(0.5f * ott);
        }
    }
}

// ---------------------------------------------------------------- masked mean-pool + l2 normalize
__global__ __launch_bounds__(384)
void pool_kernel(const float* __restrict__ x, const float* __restrict__ mask,
                 float* __restrict__ out)
{
    int b = blockIdx.x;
    int d = threadIdx.x;
    float acc = 0.f, msum = 0.f;
    for (int l = 0; l < SEQ; ++l) {
        float mk = mask[b * SEQ + l];
        acc += x[((size_t)b * SEQ + l) * DMODEL + d] * mk;
        msum += mk;
    }
    float emb = acc / fmaxf(msum, 1e-9f);
    __shared__ float red[6];
    float ss = wave_reduce_sum(emb * emb);
    int wvi = d >> 6, ln = d & 63;
    if (ln == 0) red[wvi] = ss;
    __syncthreads();
    float tot = 0.f;
    #pragma unroll
    for (int i = 0; i < 6; ++i) tot += red[i];
    float nrm = fmaxf(sqrtf(tot), 1e-12f);
    out[(size_t)b * DMODEL + d] = emb / nrm;
}

// ---------------------------------------------------------------- launch

extern "C" void kernel_launch(void* const* d_in, const int* in_sizes, int n_in,
                              void* d_out, int out_size, void* d_ws, size_t ws_size,
                              hipStream_t stream)
{
    const int*   ids   = (const int*)d_in[0];
    const float* mask  = (const float*)d_in[1];
    const float* we    = (const float*)d_in[2];
    const float* pe    = (const float*)d_in[3];
    const float* te    = (const float*)d_in[4];
    const float* elg   = (const float*)d_in[5];
    const float* elb   = (const float*)d_in[6];
    const float* Wq    = (const float*)d_in[7];
    const float* bq    = (const float*)d_in[8];
    const float* Wk    = (const float*)d_in[9];
    const float* bk    = (const float*)d_in[10];
    const float* Wv    = (const float*)d_in[11];
    const float* bv    = (const float*)d_in[12];
    const float* Wb    = (const float*)d_in[13];
    const float* dfast = (const float*)d_in[14];
    const float* dslow = (const float*)d_in[15];
    const float* Wo    = (const float*)d_in[16];
    const float* bo    = (const float*)d_in[17];
    const float* l1g   = (const float*)d_in[18];
    const float* l1b   = (const float*)d_in[19];
    const float* W1    = (const float*)d_in[20];
    const float* b1    = (const float*)d_in[21];
    const float* W2    = (const float*)d_in[22];
    const float* b2    = (const float*)d_in[23];
    const float* l2g   = (const float*)d_in[24];
    const float* l2b   = (const float*)d_in[25];
    float* out = (float*)d_out;

    // ---- workspace: 199.0 MB total (proven ceiling 202.9 MB, R4) ----
    const size_t RD = (size_t)NROWS * DMODEL;    // 12,582,912 elements
    float* x      = (float*)d_ws;                      // 50.33 MB
    float* betab  = x + RD;                            //  1.57 MB
    ushort* xb    = (ushort*)(betab + (size_t)NROWS * NH);   // 25.17 MB
    ushort* qkvb  = xb + RD;                           // 75.50 MB  [row][1152]
    ushort* ab    = qkvb + (size_t)NROWS * DQKV;       // 25.17 MB (attn out / FFN W2-out)
    ushort* WqkvT = ab + RD;                           //  5.31 MB [L][1152][384]
    ushort* WoT   = WqkvT + (size_t)NLAYER * DQKV * DMODEL;  // 1.77 MB
    ushort* W1T   = WoT + (size_t)NLAYER * DMODEL * DMODEL;  // 7.08 MB [L][1536][384]
    ushort* W2T   = W1T + (size_t)NLAYER * DMODEL * DFFN;    // 7.08 MB [L][384][1536]
    float* biasqkv = (float*)(W2T + (size_t)NLAYER * DFFN * DMODEL); // 27 KB

    dim3 blk256(256);
    dim3 rowsGrid(NROWS / 4);
    dim3 gemmGrid_QKV(NROWS / 128, DQKV / 128);      // (256, 9)
    dim3 gemmGrid_D(NROWS / 128, DMODEL / 128);      // (256, 3)
    dim3 gemmGrid_C1(FFN_CHUNK / 128, DFFN / 128);   // (128, 12)
    dim3 gemmGrid_C2(FFN_CHUNK / 128, DMODEL / 128); // (128, 3)
    dim3 chunkRows(FFN_CHUNK / 4);
    dim3 scanGrid(BATCH * NH);                       // 768 single-wave blocks

    const size_t lsQKV = (size_t)DQKV * DMODEL;
    convT_kernel<<<dim3(12, 12, NLAYER), blk256, 0, stream>>>(Wq, WqkvT, DMODEL, DMODEL, lsQKV, 0);
    convT_kernel<<<dim3(12, 12, NLAYER), blk256, 0, stream>>>(Wk, WqkvT, DMODEL, DMODEL, lsQKV, DMODEL);
    convT_kernel<<<dim3(12, 12, NLAYER), blk256, 0, stream>>>(Wv, WqkvT, DMODEL, DMODEL, lsQKV, 2*DMODEL);
    convT_kernel<<<dim3(12, 12, NLAYER), blk256, 0, stream>>>(Wo, WoT, DMODEL, DMODEL, (size_t)DMODEL*DMODEL, 0);
    convT_kernel<<<dim3(12, 48, NLAYER), blk256, 0, stream>>>(W1, W1T, DMODEL, DFFN, (size_t)DMODEL*DFFN, 0);
    convT_kernel<<<dim3(48, 12, NLAYER), blk256, 0, stream>>>(W2, W2T, DFFN, DMODEL, (size_t)DFFN*DMODEL, 0);
    biascat_kernel<<<dim3(NLAYER), dim3(384), 0, stream>>>(bq, bk, bv, biasqkv);

    embed_ln_kernel<<<rowsGrid, blk256, 0, stream>>>(ids, we, pe, te, elg, elb, x, xb);

    for (int i = 0; i < NLAYER; ++i) {
        const ushort* WqkvT_i = WqkvT + (size_t)i * lsQKV;
        const ushort* WoT_i   = WoT + (size_t)i * DMODEL * DMODEL;
        const float*  Wb_i    = Wb  + (size_t)i * DMODEL * NH;
        const ushort* W1T_i   = W1T + (size_t)i * DMODEL * DFFN;
        const ushort* W2T_i   = W2T + (size_t)i * DFFN * DMODEL;

        gemm_mfma<ushort><<<gemmGrid_QKV, blk256, 0, stream>>>(xb, WqkvT_i, biasqkv + (size_t)i * DQKV,
                                                               qkvb, NROWS, DQKV, DMODEL, DMODEL, 0);
        beta_kernel<<<rowsGrid, blk256, 0, stream>>>(xb, Wb_i, mask, betab);
        // q/k l2norm + k*mask fused into scan staging; o overwrites q-section of qkvb
        scan_kernel<<<scanGrid, dim3(64), 0, stream>>>(qkvb, betab, mask,
                                                       dfast + i * NH, dslow + i * NH, qkvb);
        // Wo GEMM reads strided o (Astride = DQKV)
        gemm_mfma<ushort><<<gemmGrid_D, blk256, 0, stream>>>(qkvb, WoT_i, bo + i * DMODEL, ab,
                                                             NROWS, DMODEL, DMODEL, DQKV, 0);
        add_ln_kernel<<<rowsGrid, blk256, 0, stream>>>(x, xb, ab, l1g + i * DMODEL, l1b + i * DMODEL);

        // FFN in 2 chunks. Chunks are SEQUENTIAL, so the h buffer is reused:
        // h -> qkvb front (25.17 MB, qkvb dead after Wo GEMM), W2-out -> ab
        // (dead after add_ln1; two chunks exactly fill ab).
        for (int c = 0; c < NROWS / FFN_CHUNK; ++c) {
            const ushort* xc = xb + (size_t)c * FFN_CHUNK * DMODEL;
            ushort* hbuf  = qkvb;                                   // reused per chunk
            ushort* w2out = ab + (size_t)c * FFN_CHUNK * DMODEL;
            gemm_mfma<ushort><<<gemmGrid_C1, blk256, 0, stream>>>(xc, W1T_i, b1 + i * DFFN, hbuf,
                                                                  FFN_CHUNK, DFFN, DMODEL, DMODEL, 1);
            gemm_mfma<ushort><<<gemmGrid_C2, blk256, 0, stream>>>(hbuf, W2T_i, b2 + i * DMODEL, w2out,
                                                                  FFN_CHUNK, DMODEL, DFFN, DFFN, 0);
            add_ln_kernel<<<chunkRows, blk256, 0, stream>>>(x + (size_t)c * FFN_CHUNK * DMODEL,
                                                            xb + (size_t)c * FFN_CHUNK * DMODEL, w2out,
                                                            l2g + i * DMODEL, l2b + i * DMODEL);
        }
    }

    pool_kernel<<<dim3(BATCH), dim3(384), 0, stream>>>(x, mask, out);
}

// Round 4
// 3300.785 us; speedup vs baseline: 1.0225x; 1.0225x over previous
//
#include <hip/hip_runtime.h>
#include <cstdint>
#include <cstddef>
#include <cmath>

#define NLAYER 6
#define NH 12
#define DMODEL 384
#define DHEAD 32
#define DFFN 1536
#define BATCH 64
#define SEQ 512
#define NROWS (BATCH*SEQ)   // 32768
#define DQKV 1152           // fused q|k|v row length
#define FFN_CHUNK 16384     // 2 chunks; h buffer reused (sequential chunks)

typedef unsigned short ushort;
typedef __attribute__((ext_vector_type(8))) short bf16x8;   // 8 bf16 = 4 VGPRs
typedef __attribute__((ext_vector_type(4))) float f32x4;

// ---------------------------------------------------------------- utilities

__device__ inline float bf2f(ushort u) {
    union { unsigned int i; float f; } c; c.i = ((unsigned int)u) << 16; return c.f;
}
__device__ inline ushort f2bf(float f) {
    union { float f; unsigned int i; } c; c.f = f;
    unsigned int i = c.i;
    unsigned int lsb = (i >> 16) & 1u;
    i += 0x7fffu + lsb;          // round-to-nearest-even
    return (ushort)(i >> 16);
}

__device__ inline float wave_reduce_sum(float v) {
    #pragma unroll
    for (int m = 32; m >= 1; m >>= 1) v += __shfl_xor(v, m, 64);
    return v;
}

__device__ inline float sigmoidf(float x) { return 1.0f / (1.0f + expf(-x)); }

__device__ inline float gelu_tanh(float x) {
    const float c = 0.7978845608028654f; // sqrt(2/pi)
    float t = tanhf(c * (x + 0.044715f * x * x * x));
    return 0.5f * x * (1.0f + t);
}

// async global->LDS, 16 bytes per lane; lds base must be wave-uniform
__device__ inline void async16(const ushort* g, ushort* l) {
    __builtin_amdgcn_global_load_lds(
        (const __attribute__((address_space(1))) unsigned int*)g,
        (__attribute__((address_space(3))) unsigned int*)l,
        16, 0, 0);
}

// ---------------------------------------------------------------- weight convert+transpose
// W fp32 [L][K][N] -> WT bf16 rows of K elements; layer stride lStride,
// dest row offset nOff (fused QKV packing).
__global__ __launch_bounds__(256)
void convT_kernel(const float* __restrict__ W, ushort* __restrict__ WT, int K, int N,
                  size_t lStride, int nOff)
{
    __shared__ float t[32][33];
    int k0 = blockIdx.x * 32, n0 = blockIdx.y * 32, L = blockIdx.z;
    const float* Wl = W + (size_t)L * K * N;
    ushort* WTl = WT + (size_t)L * lStride;
    int tx = threadIdx.x & 31, ty = threadIdx.x >> 5;   // 32 x 8
    #pragma unroll
    for (int i = 0; i < 4; ++i)
        t[ty + 8 * i][tx] = Wl[(size_t)(k0 + ty + 8 * i) * N + n0 + tx];
    __syncthreads();
    #pragma unroll
    for (int i = 0; i < 4; ++i)
        WTl[(size_t)(nOff + n0 + ty + 8 * i) * K + k0 + tx] = f2bf(t[tx][ty + 8 * i]);
}

// ---------------------------------------------------------------- fused qkv bias concat: [L][1152]
__global__ __launch_bounds__(384)
void biascat_kernel(const float* __restrict__ bq, const float* __restrict__ bk,
                    const float* __restrict__ bv, float* __restrict__ dst)
{
    int L = blockIdx.x, d = threadIdx.x;
    dst[(size_t)L * DQKV + d]             = bq[(size_t)L * DMODEL + d];
    dst[(size_t)L * DQKV + DMODEL + d]    = bk[(size_t)L * DMODEL + d];
    dst[(size_t)L * DQKV + 2*DMODEL + d]  = bv[(size_t)L * DMODEL + d];
}

// ---------------------------------------------------------------- embedding + LN (writes fp32 x and bf16 xb)
__global__ __launch_bounds__(256)
void embed_ln_kernel(const int* __restrict__ ids, const float* __restrict__ we,
                     const float* __restrict__ pe, const float* __restrict__ te,
                     const float* __restrict__ g, const float* __restrict__ bb,
                     float* __restrict__ x, ushort* __restrict__ xb)
{
    int row = blockIdx.x * 4 + (threadIdx.x >> 6);
    int lane = threadIdx.x & 63;
    int l = row & (SEQ - 1);
    int id = ids[row];
    float vals[6];
    float s = 0.f;
    #pragma unroll
    for (int t = 0; t < 6; ++t) {
        int d = lane + 64 * t;
        float v = we[(size_t)id * DMODEL + d] + pe[(size_t)l * DMODEL + d] + te[d];
        vals[t] = v; s += v;
    }
    s = wave_reduce_sum(s);
    float m = s * (1.0f / DMODEL);
    float s2 = 0.f;
    #pragma unroll
    for (int t = 0; t < 6; ++t) { float dd = vals[t] - m; s2 += dd * dd; }
    s2 = wave_reduce_sum(s2);
    float rs = rsqrtf(s2 * (1.0f / DMODEL) + 1e-12f);
    #pragma unroll
    for (int t = 0; t < 6; ++t) {
        int d = lane + 64 * t;
        float val = (vals[t] - m) * rs * g[d] + bb[d];
        x[(size_t)row * DMODEL + d] = val;
        xb[(size_t)row * DMODEL + d] = f2bf(val);
    }
}

// ---------------------------------------------------------------- residual add + LN (fp32 x in-place; bf16 branch; writes xb)
__global__ __launch_bounds__(256)
void add_ln_kernel(float* x, ushort* __restrict__ xb, const ushort* __restrict__ r,
                   const float* __restrict__ g, const float* __restrict__ bb)
{
    int row = blockIdx.x * 4 + (threadIdx.x >> 6);
    int lane = threadIdx.x & 63;
    float vals[6];
    float s = 0.f;
    #pragma unroll
    for (int t = 0; t < 6; ++t) {
        int d = lane + 64 * t;
        size_t idx = (size_t)row * DMODEL + d;
        float v = x[idx] + bf2f(r[idx]);
        vals[t] = v; s += v;
    }
    s = wave_reduce_sum(s);
    float m = s * (1.0f / DMODEL);
    float s2 = 0.f;
    #pragma unroll
    for (int t = 0; t < 6; ++t) { float dd = vals[t] - m; s2 += dd * dd; }
    s2 = wave_reduce_sum(s2);
    float rs = rsqrtf(s2 * (1.0f / DMODEL) + 1e-12f);
    #pragma unroll
    for (int t = 0; t < 6; ++t) {
        int d = lane + 64 * t;
        size_t idx = (size_t)row * DMODEL + d;
        float val = (vals[t] - m) * rs * g[d] + bb[d];
        x[idx] = val;
        xb[idx] = f2bf(val);
    }
}

// ---------------------------------------------------------------- bf16 MFMA GEMM, async-staged  [verified R7]
// A row stride Astride (elements) may differ from K (strided o-section reads).
template<typename TC>
__global__ __launch_bounds__(256)
void gemm_mfma(const ushort* __restrict__ A, const ushort* __restrict__ WT,
               const float* __restrict__ bias, TC* __restrict__ C,
               int M, int N, int K, int Astride, int act)
{
    __shared__ __align__(16) ushort As[128 * 64];   // 16 KB
    __shared__ __align__(16) ushort Bs[128 * 64];   // 16 KB
    int tid = threadIdx.x;
    int lane = tid & 63, wv = tid >> 6;
    int waveM = wv >> 1, waveN = wv & 1;
    int lm = lane & 15, quad = lane >> 4;
    int row0 = blockIdx.x * 128, col0 = blockIdx.y * 128;
    int srow = lane >> 3, sseg = lane & 7;          // staging: 8 rows x 8 segs

    f32x4 acc[4][4] = {};

    for (int k0 = 0; k0 < K; k0 += 64) {
        __syncthreads();
        #pragma unroll
        for (int i = 0; i < 4; ++i) {
            int r = wv * 32 + i * 8 + srow;
            int sg = sseg ^ (r & 7);
            async16(A  + (size_t)(row0 + r) * Astride + k0 + sg * 8, &As[(wv * 32 + i * 8) * 64]);
            async16(WT + (size_t)(col0 + r) * K + k0 + sg * 8, &Bs[(wv * 32 + i * 8) * 64]);
        }
        __syncthreads();

        #pragma unroll
        for (int ks = 0; ks < 2; ++ks) {
            int physA = ((ks * 4 + quad) ^ (lm & 7)) * 8;
            bf16x8 af[4], bf[4];
            #pragma unroll
            for (int mt = 0; mt < 4; ++mt)
                af[mt] = *(const bf16x8*)&As[(waveM * 64 + mt * 16 + lm) * 64 + physA];
            #pragma unroll
            for (int nt = 0; nt < 4; ++nt)
                bf[nt] = *(const bf16x8*)&Bs[(waveN * 64 + nt * 16 + lm) * 64 + physA];
            #pragma unroll
            for (int mt = 0; mt < 4; ++mt)
                #pragma unroll
                for (int nt = 0; nt < 4; ++nt)
                    acc[mt][nt] = __builtin_amdgcn_mfma_f32_16x16x32_bf16(af[mt], bf[nt], acc[mt][nt], 0, 0, 0);
        }
    }

    #pragma unroll
    for (int mt = 0; mt < 4; ++mt) {
        #pragma unroll
        for (int nt = 0; nt < 4; ++nt) {
            int col = col0 + waveN * 64 + nt * 16 + lm;
            float bv = bias[col];
            #pragma unroll
            for (int r = 0; r < 4; ++r) {
                int row = row0 + waveM * 64 + mt * 16 + quad * 4 + r;
                float val = acc[mt][nt][r] + bv;
                if (act == 1) val = gelu_tanh(gelu_tanh(val));
                if constexpr (sizeof(TC) == 2)
                    C[(size_t)row * N + col] = f2bf(val);
                else
                    C[(size_t)row * N + col] = val;
            }
        }
    }
}

// ---------------------------------------------------------------- beta: wave per row, coalesced bf16 x  [verified R7]
__global__ __launch_bounds__(256)
void beta_kernel(const ushort* __restrict__ xb, const float* __restrict__ Wb,
                 const float* __restrict__ mask, float* __restrict__ beta)
{
    int row = blockIdx.x * 4 + (threadIdx.x >> 6);
    int lane = threadIdx.x & 63;
    float xr[6];
    #pragma unroll
    for (int t = 0; t < 6; ++t) xr[t] = bf2f(xb[(size_t)row * DMODEL + lane + 64 * t]);
    float mine = 0.f;
    #pragma unroll
    for (int h = 0; h < NH; ++h) {
        float p = 0.f;
        #pragma unroll
        for (int t = 0; t < 6; ++t) p += xr[t] * Wb[(size_t)(lane + 64 * t) * NH + h];
        p = wave_reduce_sum(p);
        if (lane == h) mine = p;
    }
    if (lane < NH) beta[(size_t)row * NH + lane] = sigmoidf(mine) * mask[row];
}

// ---------------------------------------------------------------- delta-rule scan v7: zero cross-lane ops in the loop
// Wave serves 2 (b,h): half = lane>>5 picks bh, n = lane&31 = state column.
// Lane owns the FULL 32-deep k state for column n (float2-packed, v_pk_fma),
// so pf/ps/cf/update/o are ALL in-lane -- no shfl/bpermute anywhere in the
// inner loop (v6's shfl_xor shared lgkmcnt with ds_reads and forced ~700
// stall cyc/step at <1 wave/SIMD). Staging: lane stages full row t0+n of its
// bh, so the fused q/k l2norm + k*mask is also in-lane. Next tile is
// prefetched into registers (global loads -> vmcnt only, no lgkmcnt pollution).
// Per-step LDS reads: k/q rows are half-wave broadcasts; vs[t][n] stride-1 --
// conflict-free (2-way across halves is free).
// o writes into the q-section of qkv (rows < t0+32; prefetch reads >= t0+32).
#define SCAN_T 32
#define SPAD 36
__global__ __launch_bounds__(64)
void scan_kernel(const ushort* __restrict__ qkv, const float* __restrict__ beta,
                 const float* __restrict__ mask,
                 const float* __restrict__ dfast, const float* __restrict__ dslow,
                 ushort* __restrict__ o)
{
    __shared__ __align__(16) float qs[2][SCAN_T][SPAD];
    __shared__ __align__(16) float ks[2][SCAN_T][SPAD];
    __shared__ __align__(16) float vs[2][SCAN_T][SPAD];
    __shared__ float bs[2][SCAN_T];

    int gw = blockIdx.x;
    int lane = threadIdx.x;
    int half = lane >> 5, n = lane & 31;
    int bh = gw * 2 + half;
    int myb = bh / NH, myh = bh % NH;

    float gf = sigmoidf(dfast[myh]);
    float gsl = sigmoidf(dslow[myh]);
    float2 gf2 = make_float2(gf, gf), gs2 = make_float2(gsl, gsl);
    float2 Sf[16], Ss[16];
    #pragma unroll
    for (int j = 0; j < 16; ++j) { Sf[j] = make_float2(0.f, 0.f); Ss[j] = make_float2(0.f, 0.f); }

    // prefetch registers: tile t0=0, lane stages full row t0+n of its bh
    uint4 pq[4], pk[4], pv[4];
    float pb, pmk;
    {
        size_t ra = (size_t)(myb * SEQ + n) * DQKV + myh * DHEAD;
        #pragma unroll
        for (int s = 0; s < 4; ++s) {
            pq[s] = *(const uint4*)(qkv + ra + s * 8);
            pk[s] = *(const uint4*)(qkv + ra + DMODEL + s * 8);
            pv[s] = *(const uint4*)(qkv + ra + 2 * DMODEL + s * 8);
        }
        pb  = beta[(size_t)(myb * SEQ + n) * NH + myh];
        pmk = mask[myb * SEQ + n];
    }

    for (int t0 = 0; t0 < SEQ; t0 += SCAN_T) {
        __syncthreads();
        // ---- stage prefetched tile into LDS, fusing q/k l2norm + k*mask (in-lane)
        {
            ushort tq[32], tk[32], tv[32];
            #pragma unroll
            for (int s = 0; s < 4; ++s) {
                *(uint4*)(tq + s * 8) = pq[s];
                *(uint4*)(tk + s * 8) = pk[s];
                *(uint4*)(tv + s * 8) = pv[s];
            }
            float qv[32], kv[32];
            float sq = 0.f, sk = 0.f;
            #pragma unroll
            for (int j = 0; j < 32; ++j) {
                qv[j] = bf2f(tq[j]); sq += qv[j] * qv[j];
                kv[j] = bf2f(tk[j]); sk += kv[j] * kv[j];
            }
            float rq = 1.0f / (sqrtf(sq) + 1e-6f);
            float rk = pmk / (sqrtf(sk) + 1e-6f);
            #pragma unroll
            for (int s = 0; s < 8; ++s) {
                float4 fq, fk, fv;
                fq.x = qv[s*4+0]*rq; fq.y = qv[s*4+1]*rq; fq.z = qv[s*4+2]*rq; fq.w = qv[s*4+3]*rq;
                fk.x = kv[s*4+0]*rk; fk.y = kv[s*4+1]*rk; fk.z = kv[s*4+2]*rk; fk.w = kv[s*4+3]*rk;
                fv.x = bf2f(tv[s*4+0]); fv.y = bf2f(tv[s*4+1]); fv.z = bf2f(tv[s*4+2]); fv.w = bf2f(tv[s*4+3]);
                *(float4*)&qs[half][n][s * 4] = fq;
                *(float4*)&ks[half][n][s * 4] = fk;
                *(float4*)&vs[half][n][s * 4] = fv;
            }
            bs[half][n] = pb;
        }
        __syncthreads();

        // ---- prefetch next tile (global loads: vmcnt only, hides under compute)
        if (t0 + SCAN_T < SEQ) {
            size_t ra = (size_t)(myb * SEQ + t0 + SCAN_T + n) * DQKV + myh * DHEAD;
            #pragma unroll
            for (int s = 0; s < 4; ++s) {
                pq[s] = *(const uint4*)(qkv + ra + s * 8);
                pk[s] = *(const uint4*)(qkv + ra + DMODEL + s * 8);
                pv[s] = *(const uint4*)(qkv + ra + 2 * DMODEL + s * 8);
            }
            pb  = beta[(size_t)(myb * SEQ + t0 + SCAN_T + n) * NH + myh];
            pmk = mask[myb * SEQ + t0 + SCAN_T + n];
        }

        #pragma unroll 4
        for (int t = 0; t < SCAN_T; ++t) {
            float2 kt[16], qt[16];
            #pragma unroll
            for (int s = 0; s < 8; ++s) {
                *(float4*)&kt[s * 2] = *(const float4*)&ks[half][t][s * 4];
                *(float4*)&qt[s * 2] = *(const float4*)&qs[half][t][s * 4];
            }
            float vt = vs[half][t][n], bt = bs[half][t];

            float2 pf0 = kt[0] * Sf[0], pf1 = kt[1] * Sf[1], pf2 = kt[2] * Sf[2], pf3 = kt[3] * Sf[3];
            float2 ps0 = kt[0] * Ss[0], ps1 = kt[1] * Ss[1], ps2 = kt[2] * Ss[2], ps3 = kt[3] * Ss[3];
            #pragma unroll
            for (int j = 4; j < 16; j += 4) {
                pf0 += kt[j] * Sf[j];     pf1 += kt[j + 1] * Sf[j + 1];
                pf2 += kt[j + 2] * Sf[j + 2]; pf3 += kt[j + 3] * Sf[j + 3];
                ps0 += kt[j] * Ss[j];     ps1 += kt[j + 1] * Ss[j + 1];
                ps2 += kt[j + 2] * Ss[j + 2]; ps3 += kt[j + 3] * Ss[j + 3];
            }
            float2 pfv = (pf0 + pf1) + (pf2 + pf3);
            float2 psv = (ps0 + ps1) + (ps2 + ps3);
            float pft = pfv.x + pfv.y, pst = psv.x + psv.y;

            float cf = bt * (vt - pft), cs = bt * (vt - pst);
            float2 cf2 = make_float2(cf, cf), cs2 = make_float2(cs, cs);

            float2 o0 = make_float2(0.f, 0.f), o1 = o0, o2 = o0, o3 = o0;
            #pragma unroll
            for (int j = 0; j < 16; j += 4) {
                Sf[j] = gf2 * Sf[j] + kt[j] * cf2;         Ss[j] = gs2 * Ss[j] + kt[j] * cs2;
                Sf[j+1] = gf2 * Sf[j+1] + kt[j+1] * cf2;   Ss[j+1] = gs2 * Ss[j+1] + kt[j+1] * cs2;
                Sf[j+2] = gf2 * Sf[j+2] + kt[j+2] * cf2;   Ss[j+2] = gs2 * Ss[j+2] + kt[j+2] * cs2;
                Sf[j+3] = gf2 * Sf[j+3] + kt[j+3] * cf2;   Ss[j+3] = gs2 * Ss[j+3] + kt[j+3] * cs2;
                o0 += qt[j] * (Sf[j] + Ss[j]);
                o1 += qt[j+1] * (Sf[j+1] + Ss[j+1]);
                o2 += qt[j+2] * (Sf[j+2] + Ss[j+2]);
                o3 += qt[j+3] * (Sf[j+3] + Ss[j+3]);
            }
            float2 ov = (o0 + o1) + (o2 + o3);
            float ott = ov.x + ov.y;
            // o into q-section of qkv: row stride DQKV (both halves write their own bh)
            o[((size_t)(myb * SEQ + t0 + t)) * DQKV + myh * DHEAD + n] = f2bf(0.5f * ott);
        }
    }
}

// ---------------------------------------------------------------- masked mean-pool + l2 normalize
__global__ __launch_bounds__(384)
void pool_kernel(const float* __restrict__ x, const float* __restrict__ mask,
                 float* __restrict__ out)
{
    int b = blockIdx.x;
    int d = threadIdx.x;
    float acc = 0.f, msum = 0.f;
    for (int l = 0; l < SEQ; ++l) {
        float mk = mask[b * SEQ + l];
        acc += x[((size_t)b * SEQ + l) * DMODEL + d] * mk;
        msum += mk;
    }
    float emb = acc / fmaxf(msum, 1e-9f);
    __shared__ float red[6];
    float ss = wave_reduce_sum(emb * emb);
    int wvi = d >> 6, ln = d & 63;
    if (ln == 0) red[wvi] = ss;
    __syncthreads();
    float tot = 0.f;
    #pragma unroll
    for (int i = 0; i < 6; ++i) tot += red[i];
    float nrm = fmaxf(sqrtf(tot), 1e-12f);
    out[(size_t)b * DMODEL + d] = emb / nrm;
}

// ---------------------------------------------------------------- launch

extern "C" void kernel_launch(void* const* d_in, const int* in_sizes, int n_in,
                              void* d_out, int out_size, void* d_ws, size_t ws_size,
                              hipStream_t stream)
{
    const int*   ids   = (const int*)d_in[0];
    const float* mask  = (const float*)d_in[1];
    const float* we    = (const float*)d_in[2];
    const float* pe    = (const float*)d_in[3];
    const float* te    = (const float*)d_in[4];
    const float* elg   = (const float*)d_in[5];
    const float* elb   = (const float*)d_in[6];
    const float* Wq    = (const float*)d_in[7];
    const float* bq    = (const float*)d_in[8];
    const float* Wk    = (const float*)d_in[9];
    const float* bk    = (const float*)d_in[10];
    const float* Wv    = (const float*)d_in[11];
    const float* bv    = (const float*)d_in[12];
    const float* Wb    = (const float*)d_in[13];
    const float* dfast = (const float*)d_in[14];
    const float* dslow = (const float*)d_in[15];
    const float* Wo    = (const float*)d_in[16];
    const float* bo    = (const float*)d_in[17];
    const float* l1g   = (const float*)d_in[18];
    const float* l1b   = (const float*)d_in[19];
    const float* W1    = (const float*)d_in[20];
    const float* b1    = (const float*)d_in[21];
    const float* W2    = (const float*)d_in[22];
    const float* b2    = (const float*)d_in[23];
    const float* l2g   = (const float*)d_in[24];
    const float* l2b   = (const float*)d_in[25];
    float* out = (float*)d_out;

    // ---- workspace: 199.0 MB total (proven ceiling 202.9 MB, R4) ----
    const size_t RD = (size_t)NROWS * DMODEL;    // 12,582,912 elements
    float* x      = (float*)d_ws;                      // 50.33 MB
    float* betab  = x + RD;                            //  1.57 MB
    ushort* xb    = (ushort*)(betab + (size_t)NROWS * NH);   // 25.17 MB
    ushort* qkvb  = xb + RD;                           // 75.50 MB  [row][1152]
    ushort* ab    = qkvb + (size_t)NROWS * DQKV;       // 25.17 MB (attn out / FFN W2-out)
    ushort* WqkvT = ab + RD;                           //  5.31 MB [L][1152][384]
    ushort* WoT   = WqkvT + (size_t)NLAYER * DQKV * DMODEL;  // 1.77 MB
    ushort* W1T   = WoT + (size_t)NLAYER * DMODEL * DMODEL;  // 7.08 MB [L][1536][384]
    ushort* W2T   = W1T + (size_t)NLAYER * DMODEL * DFFN;    // 7.08 MB [L][384][1536]
    float* biasqkv = (float*)(W2T + (size_t)NLAYER * DFFN * DMODEL); // 27 KB

    dim3 blk256(256);
    dim3 rowsGrid(NROWS / 4);
    dim3 gemmGrid_QKV(NROWS / 128, DQKV / 128);      // (256, 9)
    dim3 gemmGrid_D(NROWS / 128, DMODEL / 128);      // (256, 3)
    dim3 gemmGrid_C1(FFN_CHUNK / 128, DFFN / 128);   // (128, 12)
    dim3 gemmGrid_C2(FFN_CHUNK / 128, DMODEL / 128); // (128, 3)
    dim3 chunkRows(FFN_CHUNK / 4);
    dim3 scanGrid(BATCH * NH / 2);                   // 384 single-wave blocks, 2 bh each

    const size_t lsQKV = (size_t)DQKV * DMODEL;
    convT_kernel<<<dim3(12, 12, NLAYER), blk256, 0, stream>>>(Wq, WqkvT, DMODEL, DMODEL, lsQKV, 0);
    convT_kernel<<<dim3(12, 12, NLAYER), blk256, 0, stream>>>(Wk, WqkvT, DMODEL, DMODEL, lsQKV, DMODEL);
    convT_kernel<<<dim3(12, 12, NLAYER), blk256, 0, stream>>>(Wv, WqkvT, DMODEL, DMODEL, lsQKV, 2*DMODEL);
    convT_kernel<<<dim3(12, 12, NLAYER), blk256, 0, stream>>>(Wo, WoT, DMODEL, DMODEL, (size_t)DMODEL*DMODEL, 0);
    convT_kernel<<<dim3(12, 48, NLAYER), blk256, 0, stream>>>(W1, W1T, DMODEL, DFFN, (size_t)DMODEL*DFFN, 0);
    convT_kernel<<<dim3(48, 12, NLAYER), blk256, 0, stream>>>(W2, W2T, DFFN, DMODEL, (size_t)DFFN*DMODEL, 0);
    biascat_kernel<<<dim3(NLAYER), dim3(384), 0, stream>>>(bq, bk, bv, biasqkv);

    embed_ln_kernel<<<rowsGrid, blk256, 0, stream>>>(ids, we, pe, te, elg, elb, x, xb);

    for (int i = 0; i < NLAYER; ++i) {
        const ushort* WqkvT_i = WqkvT + (size_t)i * lsQKV;
        const ushort* WoT_i   = WoT + (size_t)i * DMODEL * DMODEL;
        const float*  Wb_i    = Wb  + (size_t)i * DMODEL * NH;
        const ushort* W1T_i   = W1T + (size_t)i * DMODEL * DFFN;
        const ushort* W2T_i   = W2T + (size_t)i * DFFN * DMODEL;

        gemm_mfma<ushort><<<gemmGrid_QKV, blk256, 0, stream>>>(xb, WqkvT_i, biasqkv + (size_t)i * DQKV,
                                                               qkvb, NROWS, DQKV, DMODEL, DMODEL, 0);
        beta_kernel<<<rowsGrid, blk256, 0, stream>>>(xb, Wb_i, mask, betab);
        // q/k l2norm + k*mask fused into scan staging; o overwrites q-section of qkvb
        scan_kernel<<<scanGrid, dim3(64), 0, stream>>>(qkvb, betab, mask,
                                                       dfast + i * NH, dslow + i * NH, qkvb);
        // Wo GEMM reads strided o (Astride = DQKV)
        gemm_mfma<ushort><<<gemmGrid_D, blk256, 0, stream>>>(qkvb, WoT_i, bo + i * DMODEL, ab,
                                                             NROWS, DMODEL, DMODEL, DQKV, 0);
        add_ln_kernel<<<rowsGrid, blk256, 0, stream>>>(x, xb, ab, l1g + i * DMODEL, l1b + i * DMODEL);

        // FFN in 2 chunks. Chunks are SEQUENTIAL, so the h buffer is reused:
        // h -> qkvb front (25.17 MB, qkvb dead after Wo GEMM), W2-out -> ab
        // (dead after add_ln1; two chunks exactly fill ab).
        for (int c = 0; c < NROWS / FFN_CHUNK; ++c) {
            const ushort* xc = xb + (size_t)c * FFN_CHUNK * DMODEL;
            ushort* hbuf  = qkvb;                                   // reused per chunk
            ushort* w2out = ab + (size_t)c * FFN_CHUNK * DMODEL;
            gemm_mfma<ushort><<<gemmGrid_C1, blk256, 0, stream>>>(xc, W1T_i, b1 + i * DFFN, hbuf,
                                                                  FFN_CHUNK, DFFN, DMODEL, DMODEL, 1);
            gemm_mfma<ushort><<<gemmGrid_C2, blk256, 0, stream>>>(hbuf, W2T_i, b2 + i * DMODEL, w2out,
                                                                  FFN_CHUNK, DMODEL, DFFN, DFFN, 0);
            add_ln_kernel<<<chunkRows, blk256, 0, stream>>>(x + (size_t)c * FFN_CHUNK * DMODEL,
                                                            xb + (size_t)c * FFN_CHUNK * DMODEL, w2out,
                                                            l2g + i * DMODEL, l2b + i * DMODEL);
        }
    }

    pool_kernel<<<dim3(BATCH), dim3(384), 0, stream>>>(x, mask, out);
}